// Round 4
// baseline (4235.889 us; speedup 1.0000x reference)
//
#include <hip/hip_runtime.h>

typedef __attribute__((ext_vector_type(8))) short bf16x8;
typedef __attribute__((ext_vector_type(4))) float f32x4;

__device__ __forceinline__ float b2f(ushort u) {
    union { unsigned int i; float f; } v; v.i = ((unsigned int)u) << 16; return v.f;
}
__device__ __forceinline__ ushort f2b(float f) {
    union { float f; unsigned int i; } v; v.f = f;
    unsigned int i = v.i;
    return (ushort)((i + 0x7FFFu + ((i >> 16) & 1u)) >> 16);
}

// ---- LN2: x2(fp32 rows,1024) -> y (bf16) ----
__global__ __launch_bounds__(256) void ln_kernel(const float* __restrict__ x,
                                                 const float* __restrict__ sc,
                                                 const float* __restrict__ bi,
                                                 ushort* __restrict__ y) {
    __shared__ float red[8];
    long row = blockIdx.x;
    const float* xr = x + row * 1024;
    int t = threadIdx.x;
    float4 u = *(const float4*)(xr + t * 4);
    float s = u.x + u.y + u.z + u.w;
    float q = u.x * u.x + u.y * u.y + u.z * u.z + u.w * u.w;
    for (int off = 32; off > 0; off >>= 1) {
        s += __shfl_xor(s, off);
        q += __shfl_xor(q, off);
    }
    if ((t & 63) == 0) { red[t >> 6] = s; red[4 + (t >> 6)] = q; }
    __syncthreads();
    s = red[0] + red[1] + red[2] + red[3];
    q = red[4] + red[5] + red[6] + red[7];
    float mean = s * (1.0f / 1024.0f);
    float var = q * (1.0f / 1024.0f) - mean * mean;
    float rstd = rsqrtf(fmaxf(var, 0.0f) + 1e-6f);
    int c = t * 4;
    float o0 = (u.x - mean) * rstd * sc[c + 0] + bi[c + 0];
    float o1 = (u.y - mean) * rstd * sc[c + 1] + bi[c + 1];
    float o2 = (u.z - mean) * rstd * sc[c + 2] + bi[c + 2];
    float o3 = (u.w - mean) * rstd * sc[c + 3] + bi[c + 3];
    uint2 o;
    o.x = (unsigned int)f2b(o0) | ((unsigned int)f2b(o1) << 16);
    o.y = (unsigned int)f2b(o2) | ((unsigned int)f2b(o3) << 16);
    *(uint2*)(y + row * 1024 + c) = o;
}

// ---- fused LN1 + window partition for ONE image: x fp32 (4096,1024) -> wy bf16 (4992,1024) ----
__global__ __launch_bounds__(256) void ln_part_kernel(const float* __restrict__ x,
                                                      const float* __restrict__ sc,
                                                      const float* __restrict__ bi,
                                                      ushort* __restrict__ wy) {
    __shared__ float red[8];
    int wt = blockIdx.x;                 // 0..4991
    int wi = wt / 196, rr = wt % 196;
    int t = threadIdx.x;
    int valid = 0, gh = 0, gw = 0;
    if (wi < 25) {
        gh = (wi / 5) * 14 + rr / 14;
        gw = (wi % 5) * 14 + rr % 14;
        valid = (gh < 64 && gw < 64);
    }
    uint2 o; o.x = 0u; o.y = 0u;
    if (valid) {
        const float* xr = x + (long)(gh * 64 + gw) * 1024;
        float4 u = *(const float4*)(xr + t * 4);
        float s = u.x + u.y + u.z + u.w;
        float q = u.x * u.x + u.y * u.y + u.z * u.z + u.w * u.w;
        for (int off = 32; off > 0; off >>= 1) {
            s += __shfl_xor(s, off);
            q += __shfl_xor(q, off);
        }
        if ((t & 63) == 0) { red[t >> 6] = s; red[4 + (t >> 6)] = q; }
        __syncthreads();
        s = red[0] + red[1] + red[2] + red[3];
        q = red[4] + red[5] + red[6] + red[7];
        float mean = s * (1.0f / 1024.0f);
        float var = q * (1.0f / 1024.0f) - mean * mean;
        float rstd = rsqrtf(fmaxf(var, 0.0f) + 1e-6f);
        int c = t * 4;
        float o0 = (u.x - mean) * rstd * sc[c + 0] + bi[c + 0];
        float o1 = (u.y - mean) * rstd * sc[c + 1] + bi[c + 1];
        float o2 = (u.z - mean) * rstd * sc[c + 2] + bi[c + 2];
        float o3 = (u.w - mean) * rstd * sc[c + 3] + bi[c + 3];
        o.x = (unsigned int)f2b(o0) | ((unsigned int)f2b(o1) << 16);
        o.y = (unsigned int)f2b(o2) | ((unsigned int)f2b(o3) << 16);
    }
    *(uint2*)(wy + (long)wt * 1024 + t * 4) = o;
}

// ---- transpose + cast: in fp32 (K,N) -> out bf16 (N,K) ----
__global__ void transpose_w(const float* __restrict__ in, ushort* __restrict__ out,
                            int K, int N) {
    __shared__ float tile[32][33];
    int n0 = blockIdx.x * 32, k0 = blockIdx.y * 32;
    int tx = threadIdx.x, ty = threadIdx.y;
    for (int i = 0; i < 32; i += 8)
        tile[ty + i][tx] = in[(long)(k0 + ty + i) * N + n0 + tx];
    __syncthreads();
    for (int i = 0; i < 32; i += 8)
        out[(long)(n0 + ty + i) * K + k0 + tx] = f2b(tile[tx][ty + i]);
}

// ---- GEMM: C(M,N) = A(M,K)bf16 @ Bt(N,K)^T bf16 + bias(fp32), opt gelu / fp32-resid ----
// FLAGS bit0 = exact GELU, bit1 = add resid; OT = ushort (bf16 out) or float
#define LDA 40
template <int FLAGS, typename OT>
__global__ __launch_bounds__(256) void gemm_bt(const ushort* __restrict__ A,
                                               const ushort* __restrict__ Bt,
                                               const float* __restrict__ bias,
                                               const float* __restrict__ resid,
                                               OT* __restrict__ out,
                                               int M, int N, int K) {
    __shared__ ushort As[128 * LDA];
    __shared__ ushort Bs[128 * LDA];
    const int tid = threadIdx.x;
    const int lane = tid & 63, w = tid >> 6;
    const int wm = (w >> 1) * 64, wn = (w & 1) * 64;
    const int quad = lane >> 4, l16 = lane & 15;
    const int bm = blockIdx.x * 128, bn = blockIdx.y * 128;
    const int r = tid >> 2, kc = (tid & 3) * 8;
    f32x4 acc[4][4];
#pragma unroll
    for (int i = 0; i < 4; i++)
#pragma unroll
        for (int j = 0; j < 4; j++) acc[i][j] = (f32x4){0.f, 0.f, 0.f, 0.f};
    const ushort* Ab = A + (long)(bm + r) * K + kc;
    const ushort* Bb = Bt + (long)(bn + r) * K + kc;
    for (int k0 = 0; k0 < K; k0 += 32) {
        uint4 a0 = *(const uint4*)(Ab + k0);
        uint4 a1 = *(const uint4*)(Ab + (long)64 * K + k0);
        uint4 b0 = *(const uint4*)(Bb + k0);
        uint4 b1 = *(const uint4*)(Bb + (long)64 * K + k0);
        __syncthreads();
        *(uint4*)&As[r * LDA + kc] = a0;
        *(uint4*)&As[(r + 64) * LDA + kc] = a1;
        *(uint4*)&Bs[r * LDA + kc] = b0;
        *(uint4*)&Bs[(r + 64) * LDA + kc] = b1;
        __syncthreads();
        bf16x8 afr[4], bfr[4];
#pragma unroll
        for (int t = 0; t < 4; t++) {
            afr[t] = *(const bf16x8*)&As[(wm + t * 16 + l16) * LDA + quad * 8];
            bfr[t] = *(const bf16x8*)&Bs[(wn + t * 16 + l16) * LDA + quad * 8];
        }
#pragma unroll
        for (int tm = 0; tm < 4; tm++)
#pragma unroll
            for (int tn = 0; tn < 4; tn++)
                acc[tm][tn] = __builtin_amdgcn_mfma_f32_16x16x32_bf16(afr[tm], bfr[tn],
                                                                     acc[tm][tn], 0, 0, 0);
    }
#pragma unroll
    for (int tm = 0; tm < 4; tm++) {
#pragma unroll
        for (int j = 0; j < 4; j++) {
            int gm = bm + wm + tm * 16 + quad * 4 + j;
#pragma unroll
            for (int tn = 0; tn < 4; tn++) {
                int gn = bn + wn + tn * 16 + l16;
                float v = acc[tm][tn][j] + bias[gn];
                if (FLAGS & 1) v = 0.5f * v * (1.0f + erff(v * 0.70710678118654752f));
                if (FLAGS & 2) v += resid[(long)gm * N + gn];
                if (sizeof(OT) == 4) out[(long)gm * N + gn] = (OT)v;
                else out[(long)gm * N + gn] = (OT)f2b(v);
            }
        }
    }
}

// ---- attention per (window-in-group, head) ----
// qkv: (1024, 3072) bf16 rows = win_local*196 + token (first 980 valid)
// o_out: (4096, 1024) bf16 per-image global layout; g = window row group (0..4)
__global__ __launch_bounds__(256) void attn_kernel(const ushort* __restrict__ qkv,
                                                   ushort* __restrict__ o_out,
                                                   const float* __restrict__ relH,
                                                   const float* __restrict__ relW,
                                                   int g) {
    __shared__ ushort Vt[64 * 200];        // V^T: Vt[d][k], k<196 valid
    __shared__ ushort Ps[4 * 16 * 200];    // per-wave P tile-row, bf16
    __shared__ ushort dhw[2 * 196 * 14];   // dh then dw
    const int wl = blockIdx.x, head = blockIdx.y;
    const long qbase = (long)wl * 196 * 3072 + head * 64;
    const int tid = threadIdx.x, lane = tid & 63, w = tid >> 6;
    const int quad = lane >> 4, l16 = lane & 15;

    for (int idx = tid; idx < 196 * 64; idx += 256) {
        int k = idx >> 6, d = idx & 63;
        Vt[d * 200 + k] = qkv[qbase + 2048 + (long)k * 3072 + d];
    }
    // dh[r][i] = dot(q_r, relH[r/14 - i + 13]); dw[r][i] = dot(q_r, relW[r%14 - i + 13])
    for (int idx = tid; idx < 2 * 2744; idx += 256) {
        int which = idx / 2744;
        int rem = idx - which * 2744;
        int rr = rem / 14, ii = rem % 14;
        int qidx = (which == 0) ? (rr / 14) : (rr % 14);
        const float* tab = (which == 0) ? relH : relW;
        const ushort* qp = qkv + qbase + (long)rr * 3072;
        const float* tp = tab + (qidx - ii + 13) * 64;
        float s = 0.f;
        for (int d0 = 0; d0 < 64; d0 += 8) {
            uint4 qa = *(const uint4*)(qp + d0);
            const ushort* qh_ = (const ushort*)&qa;
#pragma unroll
            for (int e = 0; e < 8; e++) s += b2f(qh_[e]) * tp[d0 + e];
        }
        dhw[idx] = f2b(s);
    }
    __syncthreads();

    const int whh = g * 14, www = wl * 14;

    for (int tr = w; tr < 13; tr += 4) {
        int qrow = tr * 16 + l16;
        if (qrow > 195) qrow = 195;
        bf16x8 qf0 = *(const bf16x8*)(qkv + qbase + (long)qrow * 3072 + quad * 8);
        bf16x8 qf1 = *(const bf16x8*)(qkv + qbase + (long)qrow * 3072 + 32 + quad * 8);
        f32x4 sf[13];
#pragma unroll
        for (int tc = 0; tc < 13; tc++) {
            int krow = tc * 16 + l16;
            if (krow > 195) krow = 195;
            const ushort* kp = qkv + qbase + 1024 + (long)krow * 3072 + quad * 8;
            bf16x8 kf0 = *(const bf16x8*)kp;
            bf16x8 kf1 = *(const bf16x8*)(kp + 32);
            f32x4 s = (f32x4){0.f, 0.f, 0.f, 0.f};
            s = __builtin_amdgcn_mfma_f32_16x16x32_bf16(qf0, kf0, s, 0, 0, 0);
            s = __builtin_amdgcn_mfma_f32_16x16x32_bf16(qf1, kf1, s, 0, 0, 0);
            sf[tc] = s;
        }
#pragma unroll
        for (int tc = 0; tc < 13; tc++) {
            int c = tc * 16 + l16;
            if (c < 196) {
                int kh = c / 14, kw = c - kh * 14;
#pragma unroll
                for (int j = 0; j < 4; j++) {
                    int rr = tr * 16 + quad * 4 + j;
                    if (rr > 195) rr = 195;
                    sf[tc][j] = sf[tc][j] * 0.125f + b2f(dhw[rr * 14 + kh]) +
                                b2f(dhw[2744 + rr * 14 + kw]);
                }
            } else {
#pragma unroll
                for (int j = 0; j < 4; j++) sf[tc][j] = -30000.0f;
            }
        }
        f32x4 mx = sf[0];
#pragma unroll
        for (int tc = 1; tc < 13; tc++)
#pragma unroll
            for (int j = 0; j < 4; j++) mx[j] = fmaxf(mx[j], sf[tc][j]);
        for (int off = 1; off < 16; off <<= 1)
#pragma unroll
            for (int j = 0; j < 4; j++) mx[j] = fmaxf(mx[j], __shfl_xor(mx[j], off));
        f32x4 sum = (f32x4){0.f, 0.f, 0.f, 0.f};
#pragma unroll
        for (int tc = 0; tc < 13; tc++)
#pragma unroll
            for (int j = 0; j < 4; j++) {
                float p = __expf(sf[tc][j] - mx[j]);
                sf[tc][j] = p;
                sum[j] += p;
            }
        for (int off = 1; off < 16; off <<= 1)
#pragma unroll
            for (int j = 0; j < 4; j++) sum[j] += __shfl_xor(sum[j], off);
        f32x4 linv;
#pragma unroll
        for (int j = 0; j < 4; j++) linv[j] = 1.0f / sum[j];
#pragma unroll
        for (int tc = 0; tc < 13; tc++) {
            int c = tc * 16 + l16;
            if (c < 200) {
#pragma unroll
                for (int j = 0; j < 4; j++)
                    Ps[(w * 16 + quad * 4 + j) * 200 + c] = f2b(sf[tc][j]);
            }
        }
        f32x4 oa[4];
#pragma unroll
        for (int tn = 0; tn < 4; tn++) oa[tn] = (f32x4){0.f, 0.f, 0.f, 0.f};
#pragma unroll
        for (int ks = 0; ks < 6; ks++) {
            bf16x8 pf = *(const bf16x8*)&Ps[(w * 16 + l16) * 200 + ks * 32 + quad * 8];
#pragma unroll
            for (int tn = 0; tn < 4; tn++) {
                bf16x8 vf = *(const bf16x8*)&Vt[(tn * 16 + l16) * 200 + ks * 32 + quad * 8];
                oa[tn] = __builtin_amdgcn_mfma_f32_16x16x32_bf16(pf, vf, oa[tn], 0, 0, 0);
            }
        }
        for (int kk = 192; kk < 196; kk++) {
            float pj[4];
#pragma unroll
            for (int j = 0; j < 4; j++) pj[j] = b2f(Ps[(w * 16 + quad * 4 + j) * 200 + kk]);
#pragma unroll
            for (int tn = 0; tn < 4; tn++) {
                float vv = b2f(Vt[(tn * 16 + l16) * 200 + kk]);
#pragma unroll
                for (int j = 0; j < 4; j++) oa[tn][j] += pj[j] * vv;
            }
        }
#pragma unroll
        for (int j = 0; j < 4; j++) {
            int rr = tr * 16 + quad * 4 + j;
            if (rr < 196) {
                int gh = whh + rr / 14, gw = www + rr % 14;
                if (gh < 64 && gw < 64) {
                    long orow = (long)(gh * 64 + gw);
#pragma unroll
                    for (int tn = 0; tn < 4; tn++)
                        o_out[orow * 1024 + head * 64 + tn * 16 + l16] =
                            f2b(oa[tn][j] * linv[j]);
                }
            }
        }
    }
}

// ---------------- launch ----------------
extern "C" void kernel_launch(void* const* d_in, const int* in_sizes, int n_in,
                              void* d_out, int out_size, void* d_ws, size_t ws_size,
                              hipStream_t stream) {
    const float* x = (const float*)d_in[0];
    const float* n1s = (const float*)d_in[1];
    const float* n1b = (const float*)d_in[2];
    const float* qkvW = (const float*)d_in[3];
    const float* qkvB = (const float*)d_in[4];
    const float* relH = (const float*)d_in[5];
    const float* relW = (const float*)d_in[6];
    const float* projW = (const float*)d_in[7];
    const float* projB = (const float*)d_in[8];
    const float* n2s = (const float*)d_in[9];
    const float* n2b = (const float*)d_in[10];
    const float* fc1W = (const float*)d_in[11];
    const float* fc1B = (const float*)d_in[12];
    const float* fc2W = (const float*)d_in[13];
    const float* fc2B = (const float*)d_in[14];
    float* OUT = (float*)d_out;   // 16384 x 1024 fp32; holds x2 then final

    // bf16 workspace, peak ~31.2 MB
    // stage A: T0[0,6.29M) qkvT | W0[6.29,16.52M) win_y | W1[16.52,22.81M) qkv-group / projT
    //          W2[22.81,31.20M) attn_out (per image)
    // stage B: F1[0,8.39M) fc1T | F2[8.39,16.78M) fc2T | Z[16.78,18.88M) | H[18.88,27.26M)
    char* ws = (char*)d_ws;
    ushort* T0 = (ushort*)(ws);
    ushort* W0 = (ushort*)(ws + 6291456ULL);
    ushort* W1 = (ushort*)(ws + 16515072ULL);
    ushort* W2 = (ushort*)(ws + 22806528ULL);
    ushort* F1 = (ushort*)(ws);
    ushort* F2 = (ushort*)(ws + 8388608ULL);
    ushort* Z  = (ushort*)(ws + 16777216ULL);
    ushort* H  = (ushort*)(ws + 18874368ULL);

    // qkv weight transpose once: fp32 (1024,3072) -> bf16 (3072,1024)
    transpose_w<<<dim3(96, 32), dim3(32, 8), 0, stream>>>(qkvW, T0, 1024, 3072);

    for (int i = 0; i < 4; i++) {
        const float* xi = x + (long)i * 4194304;
        ln_part_kernel<<<4992, 256, 0, stream>>>(xi, n1s, n1b, W0);
        for (int g = 0; g < 5; g++) {
            gemm_bt<0, ushort><<<dim3(8, 24), 256, 0, stream>>>(
                W0 + (long)g * 980 * 1024, T0, qkvB, nullptr, W1, 1024, 3072, 1024);
            attn_kernel<<<dim3(5, 16), 256, 0, stream>>>(W1, W2, relH, relW, g);
        }
        transpose_w<<<dim3(32, 32), dim3(32, 8), 0, stream>>>(projW, W1, 1024, 1024);
        gemm_bt<2, float><<<dim3(32, 8), 256, 0, stream>>>(
            W2, W1, projB, xi, OUT + (long)i * 4194304, 4096, 1024, 1024);
    }

    // MLP, chunked at 1024 rows; x2 lives in OUT (fp32)
    transpose_w<<<dim3(128, 32), dim3(32, 8), 0, stream>>>(fc1W, F1, 1024, 4096);
    transpose_w<<<dim3(32, 128), dim3(32, 8), 0, stream>>>(fc2W, F2, 4096, 1024);
    for (int c = 0; c < 16; c++) {
        float* xc = OUT + (long)c * 1048576;
        ln_kernel<<<1024, 256, 0, stream>>>(xc, n2s, n2b, Z);
        gemm_bt<1, ushort><<<dim3(8, 32), 256, 0, stream>>>(Z, F1, fc1B, nullptr, H,
                                                            1024, 4096, 1024);
        gemm_bt<2, float><<<dim3(8, 8), 256, 0, stream>>>(H, F2, fc2B, xc, xc,
                                                          1024, 1024, 4096);
    }
}

// Round 5
// 1425.698 us; speedup vs baseline: 2.9711x; 2.9711x over previous
//
#include <hip/hip_runtime.h>

typedef __attribute__((ext_vector_type(8))) short bf16x8;
typedef __attribute__((ext_vector_type(4))) float f32x4;

__device__ __forceinline__ float b2f(ushort u) {
    union { unsigned int i; float f; } v; v.i = ((unsigned int)u) << 16; return v.f;
}
__device__ __forceinline__ ushort f2b(float f) {
    union { float f; unsigned int i; } v; v.f = f;
    unsigned int i = v.i;
    return (ushort)((i + 0x7FFFu + ((i >> 16) & 1u)) >> 16);
}

// ---- LN2: x2(fp32 rows,1024) -> y (bf16) ----
__global__ __launch_bounds__(256) void ln_kernel(const float* __restrict__ x,
                                                 const float* __restrict__ sc,
                                                 const float* __restrict__ bi,
                                                 ushort* __restrict__ y) {
    __shared__ float red[8];
    long row = blockIdx.x;
    const float* xr = x + row * 1024;
    int t = threadIdx.x;
    float4 u = *(const float4*)(xr + t * 4);
    float s = u.x + u.y + u.z + u.w;
    float q = u.x * u.x + u.y * u.y + u.z * u.z + u.w * u.w;
    for (int off = 32; off > 0; off >>= 1) {
        s += __shfl_xor(s, off);
        q += __shfl_xor(q, off);
    }
    if ((t & 63) == 0) { red[t >> 6] = s; red[4 + (t >> 6)] = q; }
    __syncthreads();
    s = red[0] + red[1] + red[2] + red[3];
    q = red[4] + red[5] + red[6] + red[7];
    float mean = s * (1.0f / 1024.0f);
    float var = q * (1.0f / 1024.0f) - mean * mean;
    float rstd = rsqrtf(fmaxf(var, 0.0f) + 1e-6f);
    int c = t * 4;
    float o0 = (u.x - mean) * rstd * sc[c + 0] + bi[c + 0];
    float o1 = (u.y - mean) * rstd * sc[c + 1] + bi[c + 1];
    float o2 = (u.z - mean) * rstd * sc[c + 2] + bi[c + 2];
    float o3 = (u.w - mean) * rstd * sc[c + 3] + bi[c + 3];
    uint2 o;
    o.x = (unsigned int)f2b(o0) | ((unsigned int)f2b(o1) << 16);
    o.y = (unsigned int)f2b(o2) | ((unsigned int)f2b(o3) << 16);
    *(uint2*)(y + row * 1024 + c) = o;
}

// ---- fused LN1 + window partition: x fp32 (full, 16384x1024) -> wy bf16 rows ----
// wy row wt: local window lwin = wt/196 (zero if lwin >= nvalid), global win = win_base+lwin
__global__ __launch_bounds__(256) void ln_part_kernel(const float* __restrict__ x,
                                                      const float* __restrict__ sc,
                                                      const float* __restrict__ bi,
                                                      ushort* __restrict__ wy,
                                                      int win_base, int nvalid) {
    __shared__ float red[8];
    int wt = blockIdx.x;
    int lwin = wt / 196, rr = wt % 196;
    int t = threadIdx.x;
    int valid = 0;
    long xrow = 0;
    if (lwin < nvalid) {
        int gwin = win_base + lwin;
        int img = gwin / 25, wrem = gwin % 25;
        int gh = (wrem / 5) * 14 + rr / 14;
        int gw = (wrem % 5) * 14 + rr % 14;
        if (gh < 64 && gw < 64) {
            valid = 1;
            xrow = (long)img * 4096 + gh * 64 + gw;
        }
    }
    uint2 o; o.x = 0u; o.y = 0u;
    if (valid) {
        const float* xr = x + xrow * 1024;
        float4 u = *(const float4*)(xr + t * 4);
        float s = u.x + u.y + u.z + u.w;
        float q = u.x * u.x + u.y * u.y + u.z * u.z + u.w * u.w;
        for (int off = 32; off > 0; off >>= 1) {
            s += __shfl_xor(s, off);
            q += __shfl_xor(q, off);
        }
        if ((t & 63) == 0) { red[t >> 6] = s; red[4 + (t >> 6)] = q; }
        __syncthreads();
        s = red[0] + red[1] + red[2] + red[3];
        q = red[4] + red[5] + red[6] + red[7];
        float mean = s * (1.0f / 1024.0f);
        float var = q * (1.0f / 1024.0f) - mean * mean;
        float rstd = rsqrtf(fmaxf(var, 0.0f) + 1e-6f);
        int c = t * 4;
        float o0 = (u.x - mean) * rstd * sc[c + 0] + bi[c + 0];
        float o1 = (u.y - mean) * rstd * sc[c + 1] + bi[c + 1];
        float o2 = (u.z - mean) * rstd * sc[c + 2] + bi[c + 2];
        float o3 = (u.w - mean) * rstd * sc[c + 3] + bi[c + 3];
        o.x = (unsigned int)f2b(o0) | ((unsigned int)f2b(o1) << 16);
        o.y = (unsigned int)f2b(o2) | ((unsigned int)f2b(o3) << 16);
    }
    *(uint2*)(wy + (long)wt * 1024 + t * 4) = o;
}

// ---- transpose + cast: in fp32 (K,N) -> out bf16 (N,K) ----
__global__ void transpose_w(const float* __restrict__ in, ushort* __restrict__ out,
                            int K, int N) {
    __shared__ float tile[32][33];
    int n0 = blockIdx.x * 32, k0 = blockIdx.y * 32;
    int tx = threadIdx.x, ty = threadIdx.y;
    for (int i = 0; i < 32; i += 8)
        tile[ty + i][tx] = in[(long)(k0 + ty + i) * N + n0 + tx];
    __syncthreads();
    for (int i = 0; i < 32; i += 8)
        out[(long)(n0 + ty + i) * K + k0 + tx] = f2b(tile[tx][ty + i]);
}

// ---- GEMM: C(M,N) = A(M,K)bf16 @ Bt(N,K)^T bf16 + bias(fp32), opt gelu / fp32-resid ----
#define LDA 40
template <int FLAGS, typename OT>
__global__ __launch_bounds__(256) void gemm_bt(const ushort* __restrict__ A,
                                               const ushort* __restrict__ Bt,
                                               const float* __restrict__ bias,
                                               const float* __restrict__ resid,
                                               OT* __restrict__ out,
                                               int M, int N, int K) {
    __shared__ ushort As[128 * LDA];
    __shared__ ushort Bs[128 * LDA];
    const int tid = threadIdx.x;
    const int lane = tid & 63, w = tid >> 6;
    const int wm = (w >> 1) * 64, wn = (w & 1) * 64;
    const int quad = lane >> 4, l16 = lane & 15;
    const int bm = blockIdx.x * 128, bn = blockIdx.y * 128;
    const int r = tid >> 2, kc = (tid & 3) * 8;
    f32x4 acc[4][4];
#pragma unroll
    for (int i = 0; i < 4; i++)
#pragma unroll
        for (int j = 0; j < 4; j++) acc[i][j] = (f32x4){0.f, 0.f, 0.f, 0.f};
    const ushort* Ab = A + (long)(bm + r) * K + kc;
    const ushort* Bb = Bt + (long)(bn + r) * K + kc;
    for (int k0 = 0; k0 < K; k0 += 32) {
        uint4 a0 = *(const uint4*)(Ab + k0);
        uint4 a1 = *(const uint4*)(Ab + (long)64 * K + k0);
        uint4 b0 = *(const uint4*)(Bb + k0);
        uint4 b1 = *(const uint4*)(Bb + (long)64 * K + k0);
        __syncthreads();
        *(uint4*)&As[r * LDA + kc] = a0;
        *(uint4*)&As[(r + 64) * LDA + kc] = a1;
        *(uint4*)&Bs[r * LDA + kc] = b0;
        *(uint4*)&Bs[(r + 64) * LDA + kc] = b1;
        __syncthreads();
        bf16x8 afr[4], bfr[4];
#pragma unroll
        for (int t = 0; t < 4; t++) {
            afr[t] = *(const bf16x8*)&As[(wm + t * 16 + l16) * LDA + quad * 8];
            bfr[t] = *(const bf16x8*)&Bs[(wn + t * 16 + l16) * LDA + quad * 8];
        }
#pragma unroll
        for (int tm = 0; tm < 4; tm++)
#pragma unroll
            for (int tn = 0; tn < 4; tn++)
                acc[tm][tn] = __builtin_amdgcn_mfma_f32_16x16x32_bf16(afr[tm], bfr[tn],
                                                                     acc[tm][tn], 0, 0, 0);
    }
#pragma unroll
    for (int tm = 0; tm < 4; tm++) {
#pragma unroll
        for (int j = 0; j < 4; j++) {
            int gm = bm + wm + tm * 16 + quad * 4 + j;
#pragma unroll
            for (int tn = 0; tn < 4; tn++) {
                int gn = bn + wn + tn * 16 + l16;
                float v = acc[tm][tn][j] + bias[gn];
                if (FLAGS & 1) v = 0.5f * v * (1.0f + erff(v * 0.70710678118654752f));
                if (FLAGS & 2) v += resid[(long)gm * N + gn];
                if (sizeof(OT) == 4) out[(long)gm * N + gn] = (OT)v;
                else out[(long)gm * N + gn] = (OT)f2b(v);
            }
        }
    }
}

// ---- attention per (window, head) ----
// qkv rows indexed by LOCAL window (blockIdx.x); global win = win0 + blockIdx.x.
// o_out row = (img*4096 + gh*64 + gw) - orow0.
__global__ __launch_bounds__(256) void attn_kernel(const ushort* __restrict__ qkv,
                                                   ushort* __restrict__ o_out,
                                                   const float* __restrict__ relH,
                                                   const float* __restrict__ relW,
                                                   int win0, long orow0) {
    __shared__ ushort Vt[64 * 200];
    __shared__ ushort Ps[4 * 16 * 200];
    __shared__ ushort dhw[2 * 196 * 14];
    const int head = blockIdx.y;
    const long qbase = (long)blockIdx.x * 196 * 3072 + head * 64;
    const int gwin = win0 + blockIdx.x;
    const int img = gwin / 25, wrem = gwin % 25;
    const int whh = (wrem / 5) * 14, www = (wrem % 5) * 14;
    const int tid = threadIdx.x, lane = tid & 63, w = tid >> 6;
    const int quad = lane >> 4, l16 = lane & 15;

    for (int idx = tid; idx < 196 * 64; idx += 256) {
        int k = idx >> 6, d = idx & 63;
        Vt[d * 200 + k] = qkv[qbase + 2048 + (long)k * 3072 + d];
    }
    for (int idx = tid; idx < 2 * 2744; idx += 256) {
        int which = idx / 2744;
        int rem = idx - which * 2744;
        int rr = rem / 14, ii = rem % 14;
        int qidx = (which == 0) ? (rr / 14) : (rr % 14);
        const float* tab = (which == 0) ? relH : relW;
        const ushort* qp = qkv + qbase + (long)rr * 3072;
        const float* tp = tab + (qidx - ii + 13) * 64;
        float s = 0.f;
        for (int d0 = 0; d0 < 64; d0 += 8) {
            uint4 qa = *(const uint4*)(qp + d0);
            const ushort* qh_ = (const ushort*)&qa;
#pragma unroll
            for (int e = 0; e < 8; e++) s += b2f(qh_[e]) * tp[d0 + e];
        }
        dhw[idx] = f2b(s);
    }
    __syncthreads();

    for (int tr = w; tr < 13; tr += 4) {
        int qrow = tr * 16 + l16;
        if (qrow > 195) qrow = 195;
        bf16x8 qf0 = *(const bf16x8*)(qkv + qbase + (long)qrow * 3072 + quad * 8);
        bf16x8 qf1 = *(const bf16x8*)(qkv + qbase + (long)qrow * 3072 + 32 + quad * 8);
        f32x4 sf[13];
#pragma unroll
        for (int tc = 0; tc < 13; tc++) {
            int krow = tc * 16 + l16;
            if (krow > 195) krow = 195;
            const ushort* kp = qkv + qbase + 1024 + (long)krow * 3072 + quad * 8;
            bf16x8 kf0 = *(const bf16x8*)kp;
            bf16x8 kf1 = *(const bf16x8*)(kp + 32);
            f32x4 s = (f32x4){0.f, 0.f, 0.f, 0.f};
            s = __builtin_amdgcn_mfma_f32_16x16x32_bf16(qf0, kf0, s, 0, 0, 0);
            s = __builtin_amdgcn_mfma_f32_16x16x32_bf16(qf1, kf1, s, 0, 0, 0);
            sf[tc] = s;
        }
#pragma unroll
        for (int tc = 0; tc < 13; tc++) {
            int c = tc * 16 + l16;
            if (c < 196) {
                int kh = c / 14, kw = c - kh * 14;
#pragma unroll
                for (int j = 0; j < 4; j++) {
                    int rr = tr * 16 + quad * 4 + j;
                    if (rr > 195) rr = 195;
                    sf[tc][j] = sf[tc][j] * 0.125f + b2f(dhw[rr * 14 + kh]) +
                                b2f(dhw[2744 + rr * 14 + kw]);
                }
            } else {
#pragma unroll
                for (int j = 0; j < 4; j++) sf[tc][j] = -30000.0f;
            }
        }
        f32x4 mx = sf[0];
#pragma unroll
        for (int tc = 1; tc < 13; tc++)
#pragma unroll
            for (int j = 0; j < 4; j++) mx[j] = fmaxf(mx[j], sf[tc][j]);
        for (int off = 1; off < 16; off <<= 1)
#pragma unroll
            for (int j = 0; j < 4; j++) mx[j] = fmaxf(mx[j], __shfl_xor(mx[j], off));
        f32x4 sum = (f32x4){0.f, 0.f, 0.f, 0.f};
#pragma unroll
        for (int tc = 0; tc < 13; tc++)
#pragma unroll
            for (int j = 0; j < 4; j++) {
                float p = __expf(sf[tc][j] - mx[j]);
                sf[tc][j] = p;
                sum[j] += p;
            }
        for (int off = 1; off < 16; off <<= 1)
#pragma unroll
            for (int j = 0; j < 4; j++) sum[j] += __shfl_xor(sum[j], off);
        f32x4 linv;
#pragma unroll
        for (int j = 0; j < 4; j++) linv[j] = 1.0f / sum[j];
#pragma unroll
        for (int tc = 0; tc < 13; tc++) {
            int c = tc * 16 + l16;
            if (c < 200) {
#pragma unroll
                for (int j = 0; j < 4; j++)
                    Ps[(w * 16 + quad * 4 + j) * 200 + c] = f2b(sf[tc][j]);
            }
        }
        f32x4 oa[4];
#pragma unroll
        for (int tn = 0; tn < 4; tn++) oa[tn] = (f32x4){0.f, 0.f, 0.f, 0.f};
#pragma unroll
        for (int ks = 0; ks < 6; ks++) {
            bf16x8 pf = *(const bf16x8*)&Ps[(w * 16 + l16) * 200 + ks * 32 + quad * 8];
#pragma unroll
            for (int tn = 0; tn < 4; tn++) {
                bf16x8 vf = *(const bf16x8*)&Vt[(tn * 16 + l16) * 200 + ks * 32 + quad * 8];
                oa[tn] = __builtin_amdgcn_mfma_f32_16x16x32_bf16(pf, vf, oa[tn], 0, 0, 0);
            }
        }
        for (int kk = 192; kk < 196; kk++) {
            float pj[4];
#pragma unroll
            for (int j = 0; j < 4; j++) pj[j] = b2f(Ps[(w * 16 + quad * 4 + j) * 200 + kk]);
#pragma unroll
            for (int tn = 0; tn < 4; tn++) {
                float vv = b2f(Vt[(tn * 16 + l16) * 200 + kk]);
#pragma unroll
                for (int j = 0; j < 4; j++) oa[tn][j] += pj[j] * vv;
            }
        }
#pragma unroll
        for (int j = 0; j < 4; j++) {
            int rr = tr * 16 + quad * 4 + j;
            if (rr < 196) {
                int gh = whh + rr / 14, gw = www + rr % 14;
                if (gh < 64 && gw < 64) {
                    long orow = (long)img * 4096 + gh * 64 + gw - orow0;
#pragma unroll
                    for (int tn = 0; tn < 4; tn++)
                        o_out[orow * 1024 + head * 64 + tn * 16 + l16] =
                            f2b(oa[tn][j] * linv[j]);
                }
            }
        }
    }
}

// ---------------- launch ----------------
extern "C" void kernel_launch(void* const* d_in, const int* in_sizes, int n_in,
                              void* d_out, int out_size, void* d_ws, size_t ws_size,
                              hipStream_t stream) {
    const float* x = (const float*)d_in[0];
    const float* n1s = (const float*)d_in[1];
    const float* n1b = (const float*)d_in[2];
    const float* qkvW = (const float*)d_in[3];
    const float* qkvB = (const float*)d_in[4];
    const float* relH = (const float*)d_in[5];
    const float* relW = (const float*)d_in[6];
    const float* projW = (const float*)d_in[7];
    const float* projB = (const float*)d_in[8];
    const float* n2s = (const float*)d_in[9];
    const float* n2b = (const float*)d_in[10];
    const float* fc1W = (const float*)d_in[11];
    const float* fc1B = (const float*)d_in[12];
    const float* fc2W = (const float*)d_in[13];
    const float* fc2B = (const float*)d_in[14];
    float* OUT = (float*)d_out;
    char* ws = (char*)d_ws;

    if (ws_size >= 221000000ULL) {
        // ---- FULL tier (peak 220.2 MB): 13 dispatches ----
        ushort* T0  = (ushort*)(ws);                      // qkvT 6.29M
        ushort* TP  = (ushort*)(ws + 6291456ULL);         // projT 2.10M
        ushort* TF1 = (ushort*)(ws + 8388608ULL);         // fc1T 8.39M
        ushort* TF2 = (ushort*)(ws + 16777216ULL);        // fc2T 8.39M
        ushort* W0  = (ushort*)(ws + 25165824ULL);        // win_y 40.37M
        ushort* QKV = (ushort*)(ws + 65536000ULL);        // qkv 121.1M
        ushort* AO  = (ushort*)(ws + 186646528ULL);       // attn_out 33.55M
        ushort* Z   = (ushort*)(ws + 25165824ULL);        // stage B (aliases W0)
        ushort* H   = (ushort*)(ws + 58720256ULL);        // stage B (aliases QKV/AO)

        transpose_w<<<dim3(96, 32), dim3(32, 8), 0, stream>>>(qkvW, T0, 1024, 3072);
        transpose_w<<<dim3(32, 32), dim3(32, 8), 0, stream>>>(projW, TP, 1024, 1024);
        transpose_w<<<dim3(128, 32), dim3(32, 8), 0, stream>>>(fc1W, TF1, 1024, 4096);
        transpose_w<<<dim3(32, 128), dim3(32, 8), 0, stream>>>(fc2W, TF2, 4096, 1024);
        ln_part_kernel<<<19712, 256, 0, stream>>>(x, n1s, n1b, W0, 0, 100);
        gemm_bt<0, ushort><<<dim3(154, 24), 256, 0, stream>>>(W0, T0, qkvB, nullptr, QKV,
                                                              19712, 3072, 1024);
        attn_kernel<<<dim3(100, 16), 256, 0, stream>>>(QKV, AO, relH, relW, 0, 0L);
        gemm_bt<2, float><<<dim3(128, 8), 256, 0, stream>>>(AO, TP, projB, x, OUT,
                                                            16384, 1024, 1024);
        ln_kernel<<<16384, 256, 0, stream>>>(OUT, n2s, n2b, Z);
        gemm_bt<1, ushort><<<dim3(128, 32), 256, 0, stream>>>(Z, TF1, fc1B, nullptr, H,
                                                              16384, 4096, 1024);
        gemm_bt<2, float><<<dim3(128, 8), 256, 0, stream>>>(H, TF2, fc2B, OUT, OUT,
                                                            16384, 1024, 4096);
    } else if (ws_size >= 100000000ULL) {
        // ---- MID tier (peak 99.6 MB): 29 dispatches ----
        ushort* T0  = (ushort*)(ws);                      // qkvT
        ushort* TP  = (ushort*)(ws + 6291456ULL);         // projT
        ushort* TF1 = (ushort*)(ws + 8388608ULL);         // fc1T
        ushort* TF2 = (ushort*)(ws + 16777216ULL);        // fc2T
        ushort* AO  = (ushort*)(ws + 25165824ULL);        // attn_out full 33.55M
        ushort* W0  = (ushort*)(ws + 58720256ULL);        // win_y chunk 10.22M
        ushort* QKV = (ushort*)(ws + 68943872ULL);        // qkv chunk 30.67M
        ushort* Z   = (ushort*)(ws + 25165824ULL);        // stage B (aliases AO)
        ushort* H   = (ushort*)(ws + 58720256ULL);        // stage B (aliases W0/QKV)

        transpose_w<<<dim3(96, 32), dim3(32, 8), 0, stream>>>(qkvW, T0, 1024, 3072);
        transpose_w<<<dim3(32, 32), dim3(32, 8), 0, stream>>>(projW, TP, 1024, 1024);
        transpose_w<<<dim3(128, 32), dim3(32, 8), 0, stream>>>(fc1W, TF1, 1024, 4096);
        transpose_w<<<dim3(32, 128), dim3(32, 8), 0, stream>>>(fc2W, TF2, 4096, 1024);
        for (int i = 0; i < 4; i++) {
            ln_part_kernel<<<4992, 256, 0, stream>>>(x, n1s, n1b, W0, i * 25, 25);
            gemm_bt<0, ushort><<<dim3(39, 24), 256, 0, stream>>>(W0, T0, qkvB, nullptr,
                                                                 QKV, 4992, 3072, 1024);
            attn_kernel<<<dim3(25, 16), 256, 0, stream>>>(QKV, AO, relH, relW, i * 25, 0L);
        }
        gemm_bt<2, float><<<dim3(128, 8), 256, 0, stream>>>(AO, TP, projB, x, OUT,
                                                            16384, 1024, 1024);
        for (int c = 0; c < 4; c++) {
            float* xc = OUT + (long)c * 4194304;
            ln_kernel<<<4096, 256, 0, stream>>>(xc, n2s, n2b, Z);
            gemm_bt<1, ushort><<<dim3(32, 32), 256, 0, stream>>>(Z, TF1, fc1B, nullptr, H,
                                                                 4096, 4096, 1024);
            gemm_bt<2, float><<<dim3(32, 8), 256, 0, stream>>>(H, TF2, fc2B, xc, xc,
                                                               4096, 1024, 4096);
        }
    } else {
        // ---- FALLBACK (proven 31.2 MB): round-4 structure ----
        ushort* T0 = (ushort*)(ws);
        ushort* W0 = (ushort*)(ws + 6291456ULL);
        ushort* W1 = (ushort*)(ws + 16515072ULL);
        ushort* W2 = (ushort*)(ws + 22806528ULL);
        ushort* F1 = (ushort*)(ws);
        ushort* F2 = (ushort*)(ws + 8388608ULL);
        ushort* Z  = (ushort*)(ws + 16777216ULL);
        ushort* H  = (ushort*)(ws + 18874368ULL);

        transpose_w<<<dim3(96, 32), dim3(32, 8), 0, stream>>>(qkvW, T0, 1024, 3072);
        for (int i = 0; i < 4; i++) {
            const float* xi = x + (long)i * 4194304;
            ln_part_kernel<<<4992, 256, 0, stream>>>(x, n1s, n1b, W0, i * 25, 25);
            for (int g = 0; g < 5; g++) {
                gemm_bt<0, ushort><<<dim3(8, 24), 256, 0, stream>>>(
                    W0 + (long)g * 980 * 1024, T0, qkvB, nullptr, W1, 1024, 3072, 1024);
                attn_kernel<<<dim3(5, 16), 256, 0, stream>>>(W1, W2, relH, relW,
                                                             i * 25 + g * 5, (long)i * 4096);
            }
            transpose_w<<<dim3(32, 32), dim3(32, 8), 0, stream>>>(projW, W1, 1024, 1024);
            gemm_bt<2, float><<<dim3(32, 8), 256, 0, stream>>>(
                W2, W1, projB, xi, OUT + (long)i * 4194304, 4096, 1024, 1024);
        }
        transpose_w<<<dim3(128, 32), dim3(32, 8), 0, stream>>>(fc1W, F1, 1024, 4096);
        transpose_w<<<dim3(32, 128), dim3(32, 8), 0, stream>>>(fc2W, F2, 4096, 1024);
        for (int c = 0; c < 16; c++) {
            float* xc = OUT + (long)c * 1048576;
            ln_kernel<<<1024, 256, 0, stream>>>(xc, n2s, n2b, Z);
            gemm_bt<1, ushort><<<dim3(8, 32), 256, 0, stream>>>(Z, F1, fc1B, nullptr, H,
                                                                1024, 4096, 1024);
            gemm_bt<2, float><<<dim3(8, 8), 256, 0, stream>>>(H, F2, fc2B, xc, xc,
                                                              1024, 1024, 4096);
        }
    }
}

// Round 6
// 1134.113 us; speedup vs baseline: 3.7350x; 1.2571x over previous
//
#include <hip/hip_runtime.h>

typedef __attribute__((ext_vector_type(8))) short bf16x8;
typedef __attribute__((ext_vector_type(4))) float f32x4;

__device__ __forceinline__ float b2f(ushort u) {
    union { unsigned int i; float f; } v; v.i = ((unsigned int)u) << 16; return v.f;
}
__device__ __forceinline__ ushort f2b(float f) {
    union { float f; unsigned int i; } v; v.f = f;
    unsigned int i = v.i;
    return (ushort)((i + 0x7FFFu + ((i >> 16) & 1u)) >> 16);
}
__device__ __forceinline__ void glds16(const ushort* g, ushort* l) {
    __builtin_amdgcn_global_load_lds((const __attribute__((address_space(1))) void*)g,
                                     (__attribute__((address_space(3))) void*)l, 16, 0, 0);
}

// ---- LN2: x2(fp32 rows,1024) -> y (bf16) ----
__global__ __launch_bounds__(256) void ln_kernel(const float* __restrict__ x,
                                                 const float* __restrict__ sc,
                                                 const float* __restrict__ bi,
                                                 ushort* __restrict__ y) {
    __shared__ float red[8];
    long row = blockIdx.x;
    const float* xr = x + row * 1024;
    int t = threadIdx.x;
    float4 u = *(const float4*)(xr + t * 4);
    float s = u.x + u.y + u.z + u.w;
    float q = u.x * u.x + u.y * u.y + u.z * u.z + u.w * u.w;
    for (int off = 32; off > 0; off >>= 1) {
        s += __shfl_xor(s, off);
        q += __shfl_xor(q, off);
    }
    if ((t & 63) == 0) { red[t >> 6] = s; red[4 + (t >> 6)] = q; }
    __syncthreads();
    s = red[0] + red[1] + red[2] + red[3];
    q = red[4] + red[5] + red[6] + red[7];
    float mean = s * (1.0f / 1024.0f);
    float var = q * (1.0f / 1024.0f) - mean * mean;
    float rstd = rsqrtf(fmaxf(var, 0.0f) + 1e-6f);
    int c = t * 4;
    float o0 = (u.x - mean) * rstd * sc[c + 0] + bi[c + 0];
    float o1 = (u.y - mean) * rstd * sc[c + 1] + bi[c + 1];
    float o2 = (u.z - mean) * rstd * sc[c + 2] + bi[c + 2];
    float o3 = (u.w - mean) * rstd * sc[c + 3] + bi[c + 3];
    uint2 o;
    o.x = (unsigned int)f2b(o0) | ((unsigned int)f2b(o1) << 16);
    o.y = (unsigned int)f2b(o2) | ((unsigned int)f2b(o3) << 16);
    *(uint2*)(y + row * 1024 + c) = o;
}

// ---- fused LN1 + window partition ----
__global__ __launch_bounds__(256) void ln_part_kernel(const float* __restrict__ x,
                                                      const float* __restrict__ sc,
                                                      const float* __restrict__ bi,
                                                      ushort* __restrict__ wy,
                                                      int win_base, int nvalid) {
    __shared__ float red[8];
    int wt = blockIdx.x;
    int lwin = wt / 196, rr = wt % 196;
    int t = threadIdx.x;
    int valid = 0;
    long xrow = 0;
    if (lwin < nvalid) {
        int gwin = win_base + lwin;
        int img = gwin / 25, wrem = gwin % 25;
        int gh = (wrem / 5) * 14 + rr / 14;
        int gw = (wrem % 5) * 14 + rr % 14;
        if (gh < 64 && gw < 64) {
            valid = 1;
            xrow = (long)img * 4096 + gh * 64 + gw;
        }
    }
    uint2 o; o.x = 0u; o.y = 0u;
    if (valid) {
        const float* xr = x + xrow * 1024;
        float4 u = *(const float4*)(xr + t * 4);
        float s = u.x + u.y + u.z + u.w;
        float q = u.x * u.x + u.y * u.y + u.z * u.z + u.w * u.w;
        for (int off = 32; off > 0; off >>= 1) {
            s += __shfl_xor(s, off);
            q += __shfl_xor(q, off);
        }
        if ((t & 63) == 0) { red[t >> 6] = s; red[4 + (t >> 6)] = q; }
        __syncthreads();
        s = red[0] + red[1] + red[2] + red[3];
        q = red[4] + red[5] + red[6] + red[7];
        float mean = s * (1.0f / 1024.0f);
        float var = q * (1.0f / 1024.0f) - mean * mean;
        float rstd = rsqrtf(fmaxf(var, 0.0f) + 1e-6f);
        int c = t * 4;
        float o0 = (u.x - mean) * rstd * sc[c + 0] + bi[c + 0];
        float o1 = (u.y - mean) * rstd * sc[c + 1] + bi[c + 1];
        float o2 = (u.z - mean) * rstd * sc[c + 2] + bi[c + 2];
        float o3 = (u.w - mean) * rstd * sc[c + 3] + bi[c + 3];
        o.x = (unsigned int)f2b(o0) | ((unsigned int)f2b(o1) << 16);
        o.y = (unsigned int)f2b(o2) | ((unsigned int)f2b(o3) << 16);
    }
    *(uint2*)(wy + (long)wt * 1024 + t * 4) = o;
}

// ---- transpose + cast: in fp32 (K,N) -> out bf16 (N,K) ----
__global__ void transpose_w(const float* __restrict__ in, ushort* __restrict__ out,
                            int K, int N) {
    __shared__ float tile[32][33];
    int n0 = blockIdx.x * 32, k0 = blockIdx.y * 32;
    int tx = threadIdx.x, ty = threadIdx.y;
    for (int i = 0; i < 32; i += 8)
        tile[ty + i][tx] = in[(long)(k0 + ty + i) * N + n0 + tx];
    __syncthreads();
    for (int i = 0; i < 32; i += 8)
        out[(long)(n0 + ty + i) * K + k0 + tx] = f2b(tile[tx][ty + i]);
}

// ---- GEMM (m97 structure): C = A(M,K) @ Bt(N,K)^T + bias, opt gelu / fp32-resid ----
template <int FLAGS, typename OT>
__global__ __launch_bounds__(256) void gemm_bt(const ushort* __restrict__ A,
                                               const ushort* __restrict__ Bt,
                                               const float* __restrict__ bias,
                                               const float* __restrict__ resid,
                                               OT* __restrict__ out,
                                               int M, int N, int K) {
    __shared__ __align__(16) ushort As[128 * 32];
    __shared__ __align__(16) ushort Bs[128 * 32];
    const int tid = threadIdx.x;
    const int lane = tid & 63, w = tid >> 6;
    const int wm = (w >> 1) * 64, wn = (w & 1) * 64;
    const int quad = lane >> 4, l16 = lane & 15;
    const int bm = blockIdx.x * 128, bn = blockIdx.y * 128;
    const int r = tid >> 2, kc = (tid & 3) * 8;
    f32x4 acc[4][4];
#pragma unroll
    for (int i = 0; i < 4; i++)
#pragma unroll
        for (int j = 0; j < 4; j++) acc[i][j] = (f32x4){0.f, 0.f, 0.f, 0.f};
    const ushort* Ag = A + (long)(bm + r) * K + kc;
    const ushort* Bg = Bt + (long)(bn + r) * K + kc;
    ushort* AsW = As + w * 512;   // wave-uniform LDS base (lane data at +lane*8 halfs)
    ushort* BsW = Bs + w * 512;
    for (int k0 = 0; k0 < K; k0 += 32) {
        __syncthreads();
        glds16(Ag + k0, AsW);
        glds16(Ag + (long)64 * K + k0, AsW + 2048);
        glds16(Bg + k0, BsW);
        glds16(Bg + (long)64 * K + k0, BsW + 2048);
        __syncthreads();
        bf16x8 afr[4], bfr[4];
#pragma unroll
        for (int t = 0; t < 4; t++) {
            afr[t] = *(const bf16x8*)&As[(wm + t * 16 + l16) * 32 + quad * 8];
            bfr[t] = *(const bf16x8*)&Bs[(wn + t * 16 + l16) * 32 + quad * 8];
        }
#pragma unroll
        for (int tm = 0; tm < 4; tm++)
#pragma unroll
            for (int tn = 0; tn < 4; tn++)
                acc[tm][tn] = __builtin_amdgcn_mfma_f32_16x16x32_bf16(afr[tm], bfr[tn],
                                                                     acc[tm][tn], 0, 0, 0);
    }
#pragma unroll
    for (int tm = 0; tm < 4; tm++) {
#pragma unroll
        for (int j = 0; j < 4; j++) {
            int gm = bm + wm + tm * 16 + quad * 4 + j;
#pragma unroll
            for (int tn = 0; tn < 4; tn++) {
                int gn = bn + wn + tn * 16 + l16;
                float v = acc[tm][tn][j] + bias[gn];
                if (FLAGS & 1) v = 0.5f * v * (1.0f + erff(v * 0.70710678118654752f));
                if (FLAGS & 2) v += resid[(long)gm * N + gn];
                if (sizeof(OT) == 4) out[(long)gm * N + gn] = (OT)v;
                else out[(long)gm * N + gn] = (OT)f2b(v);
            }
        }
    }
}

// ---- attention per (window, head): rel-pos via MFMA, 46 KB LDS ----
__global__ __launch_bounds__(256) void attn_kernel(const ushort* __restrict__ qkv,
                                                   ushort* __restrict__ o_out,
                                                   const float* __restrict__ relH,
                                                   const float* __restrict__ relW,
                                                   int win0, long orow0) {
    __shared__ __align__(16) ushort Vt[64 * 200];    // V^T, 25.6 KB
    __shared__ __align__(16) ushort Ps[64 * 104];    // P half-tiles, 13.3 KB
    __shared__ __align__(16) ushort sc[8 * 448];     // per-wave Dh/Dw 16x28 tiles, 7 KB
    const int head = blockIdx.y;
    const long qbase = (long)blockIdx.x * 196 * 3072 + head * 64;
    const int gwin = win0 + blockIdx.x;
    const int img = gwin / 25, wrem = gwin % 25;
    const int whh = (wrem / 5) * 14, www = (wrem % 5) * 14;
    const int tid = threadIdx.x, lane = tid & 63, w = tid >> 6;
    const int quad = lane >> 4, l16 = lane & 15;

    // stage V^T
    for (int idx = tid; idx < 196 * 64; idx += 256) {
        int k = idx >> 6, d = idx & 63;
        Vt[d * 200 + k] = qkv[qbase + 2048 + (long)k * 3072 + d];
    }
    __syncthreads();

    // hoisted rel-table B-fragments: B[n=l16-of-tile][k=quad*8+e]
    bf16x8 bH[2][2], bW[2][2];
#pragma unroll
    for (int nt = 0; nt < 2; nt++) {
        int n = nt * 16 + l16;
#pragma unroll
        for (int kt = 0; kt < 2; kt++) {
            bf16x8 rh = (bf16x8){0, 0, 0, 0, 0, 0, 0, 0};
            bf16x8 rw = (bf16x8){0, 0, 0, 0, 0, 0, 0, 0};
            if (n < 27) {
                const float* ph = relH + n * 64 + kt * 32 + quad * 8;
                const float* pw = relW + n * 64 + kt * 32 + quad * 8;
#pragma unroll
                for (int e = 0; e < 8; e++) {
                    rh[e] = (short)f2b(ph[e]);
                    rw[e] = (short)f2b(pw[e]);
                }
            }
            bH[nt][kt] = rh;
            bW[nt][kt] = rw;
        }
    }

    for (int tr = w; tr < 13; tr += 4) {
        int qrow = tr * 16 + l16;
        if (qrow > 195) qrow = 195;
        bf16x8 qf0 = *(const bf16x8*)(qkv + qbase + (long)qrow * 3072 + quad * 8);
        bf16x8 qf1 = *(const bf16x8*)(qkv + qbase + (long)qrow * 3072 + 32 + quad * 8);

        // Dh/Dw tiles for this Q-tile via MFMA -> per-wave scratch
#pragma unroll
        for (int tab = 0; tab < 2; tab++) {
#pragma unroll
            for (int nt = 0; nt < 2; nt++) {
                f32x4 a = (f32x4){0.f, 0.f, 0.f, 0.f};
                a = __builtin_amdgcn_mfma_f32_16x16x32_bf16(qf0, tab ? bW[nt][0] : bH[nt][0],
                                                            a, 0, 0, 0);
                a = __builtin_amdgcn_mfma_f32_16x16x32_bf16(qf1, tab ? bW[nt][1] : bH[nt][1],
                                                            a, 0, 0, 0);
                int col = nt * 16 + l16;
                if (col < 27) {
#pragma unroll
                    for (int j = 0; j < 4; j++)
                        sc[(w * 2 + tab) * 448 + (quad * 4 + j) * 28 + col] = f2b(a[j]);
                }
            }
        }

        // QK^T logits
        f32x4 sf[13];
#pragma unroll
        for (int tc = 0; tc < 13; tc++) {
            int krow = tc * 16 + l16;
            if (krow > 195) krow = 195;
            const ushort* kp = qkv + qbase + 1024 + (long)krow * 3072 + quad * 8;
            bf16x8 kf0 = *(const bf16x8*)kp;
            bf16x8 kf1 = *(const bf16x8*)(kp + 32);
            f32x4 s = (f32x4){0.f, 0.f, 0.f, 0.f};
            s = __builtin_amdgcn_mfma_f32_16x16x32_bf16(qf0, kf0, s, 0, 0, 0);
            s = __builtin_amdgcn_mfma_f32_16x16x32_bf16(qf1, kf1, s, 0, 0, 0);
            sf[tc] = s;
        }
        // scale + rel-pos (from scratch) + key mask
#pragma unroll
        for (int tc = 0; tc < 13; tc++) {
            int c = tc * 16 + l16;
            if (c < 196) {
                int kh = c / 14, kw = c - kh * 14;
#pragma unroll
                for (int j = 0; j < 4; j++) {
                    int rr = tr * 16 + quad * 4 + j;
                    if (rr > 195) rr = 195;
                    float dh = b2f(sc[(w * 2 + 0) * 448 + (quad * 4 + j) * 28 +
                                      (rr / 14 - kh + 13)]);
                    float dw = b2f(sc[(w * 2 + 1) * 448 + (quad * 4 + j) * 28 +
                                      (rr % 14 - kw + 13)]);
                    sf[tc][j] = sf[tc][j] * 0.125f + dh + dw;
                }
            } else {
#pragma unroll
                for (int j = 0; j < 4; j++) sf[tc][j] = -30000.0f;
            }
        }
        // softmax
        f32x4 mx = sf[0];
#pragma unroll
        for (int tc = 1; tc < 13; tc++)
#pragma unroll
            for (int j = 0; j < 4; j++) mx[j] = fmaxf(mx[j], sf[tc][j]);
        for (int off = 1; off < 16; off <<= 1)
#pragma unroll
            for (int j = 0; j < 4; j++) mx[j] = fmaxf(mx[j], __shfl_xor(mx[j], off));
        f32x4 sum = (f32x4){0.f, 0.f, 0.f, 0.f};
#pragma unroll
        for (int tc = 0; tc < 13; tc++)
#pragma unroll
            for (int j = 0; j < 4; j++) {
                float p = __expf(sf[tc][j] - mx[j]);
                sf[tc][j] = p;
                sum[j] += p;
            }
        for (int off = 1; off < 16; off <<= 1)
#pragma unroll
            for (int j = 0; j < 4; j++) sum[j] += __shfl_xor(sum[j], off);
        f32x4 linv;
#pragma unroll
        for (int j = 0; j < 4; j++) linv[j] = 1.0f / sum[j];

        f32x4 oa[4];
#pragma unroll
        for (int tn = 0; tn < 4; tn++) oa[tn] = (f32x4){0.f, 0.f, 0.f, 0.f};
        // PV half 1: keys 0..95
#pragma unroll
        for (int tc = 0; tc < 6; tc++) {
            int c = tc * 16 + l16;
#pragma unroll
            for (int j = 0; j < 4; j++)
                Ps[(w * 16 + quad * 4 + j) * 104 + c] = f2b(sf[tc][j]);
        }
#pragma unroll
        for (int ks = 0; ks < 3; ks++) {
            bf16x8 pf = *(const bf16x8*)&Ps[(w * 16 + l16) * 104 + ks * 32 + quad * 8];
#pragma unroll
            for (int tn = 0; tn < 4; tn++) {
                bf16x8 vf = *(const bf16x8*)&Vt[(tn * 16 + l16) * 200 + ks * 32 + quad * 8];
                oa[tn] = __builtin_amdgcn_mfma_f32_16x16x32_bf16(pf, vf, oa[tn], 0, 0, 0);
            }
        }
        // PV half 2: keys 96..191 (+ tail 192..195 at cols 96..99)
#pragma unroll
        for (int tc = 6; tc < 13; tc++) {
            int c = tc * 16 + l16;
            if (c < 196) {
#pragma unroll
                for (int j = 0; j < 4; j++)
                    Ps[(w * 16 + quad * 4 + j) * 104 + (c - 96)] = f2b(sf[tc][j]);
            }
        }
#pragma unroll
        for (int ks = 0; ks < 3; ks++) {
            bf16x8 pf = *(const bf16x8*)&Ps[(w * 16 + l16) * 104 + ks * 32 + quad * 8];
#pragma unroll
            for (int tn = 0; tn < 4; tn++) {
                bf16x8 vf = *(const bf16x8*)&Vt[(tn * 16 + l16) * 200 + 96 + ks * 32 + quad * 8];
                oa[tn] = __builtin_amdgcn_mfma_f32_16x16x32_bf16(pf, vf, oa[tn], 0, 0, 0);
            }
        }
        for (int kk = 192; kk < 196; kk++) {
            float pj[4];
#pragma unroll
            for (int j = 0; j < 4; j++)
                pj[j] = b2f(Ps[(w * 16 + quad * 4 + j) * 104 + 96 + (kk - 192)]);
#pragma unroll
            for (int tn = 0; tn < 4; tn++) {
                float vv = b2f(Vt[(tn * 16 + l16) * 200 + kk]);
#pragma unroll
                for (int j = 0; j < 4; j++) oa[tn][j] += pj[j] * vv;
            }
        }
        // store O
#pragma unroll
        for (int j = 0; j < 4; j++) {
            int rr = tr * 16 + quad * 4 + j;
            if (rr < 196) {
                int gh = whh + rr / 14, gw = www + rr % 14;
                if (gh < 64 && gw < 64) {
                    long orow = (long)img * 4096 + gh * 64 + gw - orow0;
#pragma unroll
                    for (int tn = 0; tn < 4; tn++)
                        o_out[orow * 1024 + head * 64 + tn * 16 + l16] =
                            f2b(oa[tn][j] * linv[j]);
                }
            }
        }
    }
}

// ---------------- launch ----------------
extern "C" void kernel_launch(void* const* d_in, const int* in_sizes, int n_in,
                              void* d_out, int out_size, void* d_ws, size_t ws_size,
                              hipStream_t stream) {
    const float* x = (const float*)d_in[0];
    const float* n1s = (const float*)d_in[1];
    const float* n1b = (const float*)d_in[2];
    const float* qkvW = (const float*)d_in[3];
    const float* qkvB = (const float*)d_in[4];
    const float* relH = (const float*)d_in[5];
    const float* relW = (const float*)d_in[6];
    const float* projW = (const float*)d_in[7];
    const float* projB = (const float*)d_in[8];
    const float* n2s = (const float*)d_in[9];
    const float* n2b = (const float*)d_in[10];
    const float* fc1W = (const float*)d_in[11];
    const float* fc1B = (const float*)d_in[12];
    const float* fc2W = (const float*)d_in[13];
    const float* fc2B = (const float*)d_in[14];
    float* OUT = (float*)d_out;
    char* ws = (char*)d_ws;

    if (ws_size >= 221000000ULL) {
        // ---- FULL tier (peak 220.2 MB): 11 dispatches ----
        ushort* T0  = (ushort*)(ws);
        ushort* TP  = (ushort*)(ws + 6291456ULL);
        ushort* TF1 = (ushort*)(ws + 8388608ULL);
        ushort* TF2 = (ushort*)(ws + 16777216ULL);
        ushort* W0  = (ushort*)(ws + 25165824ULL);
        ushort* QKV = (ushort*)(ws + 65536000ULL);
        ushort* AO  = (ushort*)(ws + 186646528ULL);
        ushort* Z   = (ushort*)(ws + 25165824ULL);
        ushort* H   = (ushort*)(ws + 58720256ULL);

        transpose_w<<<dim3(96, 32), dim3(32, 8), 0, stream>>>(qkvW, T0, 1024, 3072);
        transpose_w<<<dim3(32, 32), dim3(32, 8), 0, stream>>>(projW, TP, 1024, 1024);
        transpose_w<<<dim3(128, 32), dim3(32, 8), 0, stream>>>(fc1W, TF1, 1024, 4096);
        transpose_w<<<dim3(32, 128), dim3(32, 8), 0, stream>>>(fc2W, TF2, 4096, 1024);
        ln_part_kernel<<<19712, 256, 0, stream>>>(x, n1s, n1b, W0, 0, 100);
        gemm_bt<0, ushort><<<dim3(154, 24), 256, 0, stream>>>(W0, T0, qkvB, nullptr, QKV,
                                                              19712, 3072, 1024);
        attn_kernel<<<dim3(100, 16), 256, 0, stream>>>(QKV, AO, relH, relW, 0, 0L);
        gemm_bt<2, float><<<dim3(128, 8), 256, 0, stream>>>(AO, TP, projB, x, OUT,
                                                            16384, 1024, 1024);
        ln_kernel<<<16384, 256, 0, stream>>>(OUT, n2s, n2b, Z);
        gemm_bt<1, ushort><<<dim3(128, 32), 256, 0, stream>>>(Z, TF1, fc1B, nullptr, H,
                                                              16384, 4096, 1024);
        gemm_bt<2, float><<<dim3(128, 8), 256, 0, stream>>>(H, TF2, fc2B, OUT, OUT,
                                                            16384, 1024, 4096);
    } else if (ws_size >= 100000000ULL) {
        // ---- MID tier (peak 99.6 MB) ----
        ushort* T0  = (ushort*)(ws);
        ushort* TP  = (ushort*)(ws + 6291456ULL);
        ushort* TF1 = (ushort*)(ws + 8388608ULL);
        ushort* TF2 = (ushort*)(ws + 16777216ULL);
        ushort* AO  = (ushort*)(ws + 25165824ULL);
        ushort* W0  = (ushort*)(ws + 58720256ULL);
        ushort* QKV = (ushort*)(ws + 68943872ULL);
        ushort* Z   = (ushort*)(ws + 25165824ULL);
        ushort* H   = (ushort*)(ws + 58720256ULL);

        transpose_w<<<dim3(96, 32), dim3(32, 8), 0, stream>>>(qkvW, T0, 1024, 3072);
        transpose_w<<<dim3(32, 32), dim3(32, 8), 0, stream>>>(projW, TP, 1024, 1024);
        transpose_w<<<dim3(128, 32), dim3(32, 8), 0, stream>>>(fc1W, TF1, 1024, 4096);
        transpose_w<<<dim3(32, 128), dim3(32, 8), 0, stream>>>(fc2W, TF2, 4096, 1024);
        for (int i = 0; i < 4; i++) {
            ln_part_kernel<<<4992, 256, 0, stream>>>(x, n1s, n1b, W0, i * 25, 25);
            gemm_bt<0, ushort><<<dim3(39, 24), 256, 0, stream>>>(W0, T0, qkvB, nullptr,
                                                                 QKV, 4992, 3072, 1024);
            attn_kernel<<<dim3(25, 16), 256, 0, stream>>>(QKV, AO, relH, relW, i * 25, 0L);
        }
        gemm_bt<2, float><<<dim3(128, 8), 256, 0, stream>>>(AO, TP, projB, x, OUT,
                                                            16384, 1024, 1024);
        for (int c = 0; c < 4; c++) {
            float* xc = OUT + (long)c * 4194304;
            ln_kernel<<<4096, 256, 0, stream>>>(xc, n2s, n2b, Z);
            gemm_bt<1, ushort><<<dim3(32, 32), 256, 0, stream>>>(Z, TF1, fc1B, nullptr, H,
                                                                 4096, 4096, 1024);
            gemm_bt<2, float><<<dim3(32, 8), 256, 0, stream>>>(H, TF2, fc2B, xc, xc,
                                                               4096, 1024, 4096);
        }
    } else {
        // ---- FALLBACK (proven 31.2 MB) ----
        ushort* T0 = (ushort*)(ws);
        ushort* W0 = (ushort*)(ws + 6291456ULL);
        ushort* W1 = (ushort*)(ws + 16515072ULL);
        ushort* W2 = (ushort*)(ws + 22806528ULL);
        ushort* F1 = (ushort*)(ws);
        ushort* F2 = (ushort*)(ws + 8388608ULL);
        ushort* Z  = (ushort*)(ws + 16777216ULL);
        ushort* H  = (ushort*)(ws + 18874368ULL);

        transpose_w<<<dim3(96, 32), dim3(32, 8), 0, stream>>>(qkvW, T0, 1024, 3072);
        for (int i = 0; i < 4; i++) {
            const float* xi = x + (long)i * 4194304;
            ln_part_kernel<<<4992, 256, 0, stream>>>(x, n1s, n1b, W0, i * 25, 25);
            for (int g = 0; g < 5; g++) {
                gemm_bt<0, ushort><<<dim3(8, 24), 256, 0, stream>>>(
                    W0 + (long)g * 980 * 1024, T0, qkvB, nullptr, W1, 1024, 3072, 1024);
                attn_kernel<<<dim3(5, 16), 256, 0, stream>>>(W1, W2, relH, relW,
                                                             i * 25 + g * 5, (long)i * 4096);
            }
            transpose_w<<<dim3(32, 32), dim3(32, 8), 0, stream>>>(projW, W1, 1024, 1024);
            gemm_bt<2, float><<<dim3(32, 8), 256, 0, stream>>>(
                W2, W1, projB, xi, OUT + (long)i * 4194304, 4096, 1024, 1024);
        }
        transpose_w<<<dim3(128, 32), dim3(32, 8), 0, stream>>>(fc1W, F1, 1024, 4096);
        transpose_w<<<dim3(32, 128), dim3(32, 8), 0, stream>>>(fc2W, F2, 4096, 1024);
        for (int c = 0; c < 16; c++) {
            float* xc = OUT + (long)c * 1048576;
            ln_kernel<<<1024, 256, 0, stream>>>(xc, n2s, n2b, Z);
            gemm_bt<1, ushort><<<dim3(8, 32), 256, 0, stream>>>(Z, F1, fc1B, nullptr, H,
                                                                1024, 4096, 1024);
            gemm_bt<2, float><<<dim3(8, 8), 256, 0, stream>>>(H, F2, fc2B, xc, xc,
                                                              1024, 1024, 4096);
        }
    }
}